// Round 10
// baseline (66.368 us; speedup 1.0000x reference)
//
#include <hip/hip_runtime.h>

#define W     768
#define PIX   (768*768)
#define NMAPS 16            // 0..7 anno, 8..15 pred-argmax
#define TROWS 6
#define TPX   (TROWS*W)     // 4608 px per tile
#define NT    (768/TROWS)   // 128 tiles per map
#define NB    (NT-1)        // 127 tile boundaries per map
#define STRIP 256           // columns per wave strip (64 lanes x 4 px)
#define CSLOT 16            // ints per counter slot (64 B line)

// Labels are PACKED everywhere: (label<<2) | cls. Within a component all
// pixels share cls, and min over packed == min over label -> cls bits are
// invariant under atomicMin unions.

__device__ __forceinline__ int find_root_p(volatile int* L, int x) {
    int y = L[x] >> 2;
    while (y != x) { x = y; y = L[x] >> 2; }
    return x;
}

__device__ __forceinline__ void unite_p(int* L, int a, int b, int c) {
    volatile int* Lv = L;
    while (true) {
        a = find_root_p(Lv, a);
        b = find_root_p(Lv, b);
        if (a == b) return;
        if (a > b) { int t = a; a = b; b = t; }
        int old = atomicMin(&L[b], (a << 2) | c);
        if ((old >> 2) == b) return;
        b = old >> 2;
    }
}

// Packed global unite; true iff a link event occurred (two roots merged).
// Parents only decrease -> acyclic; each index loses rootness at most once,
// so #link events == #merges exactly, independent of atomic ordering.
__device__ __forceinline__ bool unite_gp(int* L, int a, int b, int c) {
    volatile int* Lv = L;
    while (true) {
        a = find_root_p(Lv, a);
        b = find_root_p(Lv, b);
        if (a == b) return false;
        if (a > b) { int t = a; a = b; b = t; }
        int old = atomicMin(&L[b], (a << 2) | c);
        if ((old >> 2) == b) return true;
        b = old >> 2;
    }
}

// ---------------- kernels ----------------

// One block per (map, 6-row tile), 192 threads = 3 waves. Wave w owns the
// 256-col strip [256w, 256w+256) of EVERY row (4 px/lane via int4/float4
// loads) -> vertical neighbors are same-wave; per-run-pair vertical unions
// fire inside phase A from register-carried prev-row state. Horizontal runs
// init via 4 ballots/row (breaks only at strip edges; 12 stitches/tile fix
// those after the barrier). Same-wave DS ops execute in issue order, so no
// explicit lgkmcnt needed pre-barrier. Phase 3 writes SPARSE global labels:
// tile-boundary rows (root-compressed) + root self-pointers elsewhere.
__global__ __launch_bounds__(192, 6) void fused_k(const float* __restrict__ pred,
                                                  const int*   __restrict__ anno,
                                                  int* __restrict__ labels,
                                                  int* __restrict__ counts, int m0) {
    __shared__ int lab[TPX];               // 18 KB packed (label<<2)|cls
    __shared__ int s2[3], s3[3];

    int mc   = blockIdx.x / NT;
    int t    = blockIdx.x - mc * NT;
    int m    = m0 + mc;
    int tid  = threadIdx.x;
    int wid  = tid / 64;                   // strip index 0..2
    int lane = tid & 63;
    int p    = lane * 4;                   // strip-local px of component 0

    unsigned long long ltm = (1ULL << lane) - 1;        // lanes < lane
    unsigned long long lem = ltm | (1ULL << lane);      // lanes <= lane

    const int*   asrc = anno + (size_t)m * PIX + (size_t)t * TPX;
    const float* psrc = pred + (size_t)(m < 8 ? 0 : (m - 8)) * 4 * PIX + (size_t)t * TPX;
    bool is_anno = (m < 8);

    int pcc = 0, prs = 0;                  // prev-row classes (2b x4) / run-starts (8b x4)

    // ---- phase A: decode 4 px/lane, run-start init, vertical unions ----
    #pragma unroll
    for (int r = 0; r < TROWS; ++r) {
        int base = r * W + wid * STRIP;    // tile-local base of this strip-row
        int px0  = base + p;
        int c0, c1, c2, c3;
        if (is_anno) {
            int4 v = *(const int4*)&asrc[px0];
            c0 = v.x & 3; c1 = v.y & 3; c2 = v.z & 3; c3 = v.w & 3;
        } else {
            const float4* f = (const float4*)psrc;
            int i4 = px0 >> 2;
            float4 v0 = f[i4];
            float4 v1 = f[(PIX >> 2) + i4];
            float4 v2 = f[2 * (PIX >> 2) + i4];
            float4 v3 = f[3 * (PIX >> 2) + i4];
            // strict '>' = first-max (jnp.argmax)
            {   float bv = v0.x; c0 = 0;
                if (v1.x > bv) { bv = v1.x; c0 = 1; }
                if (v2.x > bv) { bv = v2.x; c0 = 2; }
                if (v3.x > bv) { bv = v3.x; c0 = 3; } }
            {   float bv = v0.y; c1 = 0;
                if (v1.y > bv) { bv = v1.y; c1 = 1; }
                if (v2.y > bv) { bv = v2.y; c1 = 2; }
                if (v3.y > bv) { bv = v3.y; c1 = 3; } }
            {   float bv = v0.z; c2 = 0;
                if (v1.z > bv) { bv = v1.z; c2 = 1; }
                if (v2.z > bv) { bv = v2.z; c2 = 2; }
                if (v3.z > bv) { bv = v3.z; c2 = 3; } }
            {   float bv = v0.w; c3 = 0;
                if (v1.w > bv) { bv = v1.w; c3 = 1; }
                if (v2.w > bv) { bv = v2.w; c3 = 2; }
                if (v3.w > bv) { bv = v3.w; c3 = 3; } }
        }
        int prev3 = __shfl_up(c3, 1);      // lane-1's last class (garbage at lane 0, masked)
        bool sf0 = (lane == 0) || (c0 != prev3);
        bool sf1 = (c1 != c0), sf2 = (c2 != c1), sf3 = (c3 != c2);
        unsigned long long b0 = __ballot(sf0);
        unsigned long long b1 = __ballot(sf1);
        unsigned long long b2 = __ballot(sf2);
        unsigned long long b3 = __ballot(sf3);
        // last start <= (lane,0): plane0 <= lane; planes 1-3 strictly < lane.
        int rs0 = (63 - __clzll(b0 & lem)) * 4;          // b0 bit0 always set
        unsigned long long mm;
        mm = b1 & ltm; if (mm) { int q = (63 - __clzll(mm)) * 4 + 1; if (q > rs0) rs0 = q; }
        mm = b2 & ltm; if (mm) { int q = (63 - __clzll(mm)) * 4 + 2; if (q > rs0) rs0 = q; }
        mm = b3 & ltm; if (mm) { int q = (63 - __clzll(mm)) * 4 + 3; if (q > rs0) rs0 = q; }
        int rs1 = sf1 ? p + 1 : rs0;
        int rs2 = sf2 ? p + 2 : rs1;
        int rs3 = sf3 ? p + 3 : rs2;
        int lb  = (base << 2);             // tile-local strip base, pre-shifted
        int4 ov = make_int4(lb + (rs0 << 2) + c0, lb + (rs1 << 2) + c1,
                            lb + (rs2 << 2) + c2, lb + (rs3 << 2) + c3);
        *(int4*)&lab[px0] = ov;
        if (r > 0) {                       // vertical per-run-pair unions (same wave)
            int pc0 = pcc & 3, pc1 = (pcc >> 2) & 3, pc2 = (pcc >> 4) & 3, pc3 = (pcc >> 6) & 3;
            int pr0 = prs & 255, pr1 = (prs >> 8) & 255, pr2 = (prs >> 16) & 255, pr3 = (prs >> 24) & 255;
            if ((c0 & 2) && c0 == pc0) { int mx = rs0 > pr0 ? rs0 : pr0; if (mx == p)     unite_p(lab, px0 - W,     px0,     c0); }
            if ((c1 & 2) && c1 == pc1) { int mx = rs1 > pr1 ? rs1 : pr1; if (mx == p + 1) unite_p(lab, px0 + 1 - W, px0 + 1, c1); }
            if ((c2 & 2) && c2 == pc2) { int mx = rs2 > pr2 ? rs2 : pr2; if (mx == p + 2) unite_p(lab, px0 + 2 - W, px0 + 2, c2); }
            if ((c3 & 2) && c3 == pc3) { int mx = rs3 > pr3 ? rs3 : pr3; if (mx == p + 3) unite_p(lab, px0 + 3 - W, px0 + 3, c3); }
        }
        pcc = c0 | (c1 << 2) | (c2 << 4) | (c3 << 6);
        prs = rs0 | (rs1 << 8) | (rs2 << 16) | (rs3 << 24);
    }
    __syncthreads();

    // ---- stitch phase: 12 cross-strip horizontal joins ----
    if (tid < TROWS * 2) {
        int row = tid >> 1, s = (tid & 1) + 1;
        int px  = row * W + s * STRIP;
        int v = lab[px], c = v & 3;
        if (c & 2) {
            int vl = lab[px - 1];
            if ((vl & 3) == c) unite_p(lab, px - 1, px, c);
        }
    }
    __syncthreads();

    // ---- phase 3: count roots (1 read, no find), sparse label writes ----
    int n2 = 0, n3 = 0;
    int lbase = t * TPX;                   // map-local base of this tile
    int* gl = labels + (size_t)mc * PIX + lbase;
    #pragma unroll
    for (int r = 0; r < TROWS; ++r) {
        int px0 = r * W + wid * STRIP + p;
        int4 v = *(int4*)&lab[px0];
        int c0 = v.x & 3, c1 = v.y & 3, c2 = v.z & 3, c3 = v.w & 3;
        bool r0 = (c0 & 2) && (v.x >> 2) == px0;
        bool r1 = (c1 & 2) && (v.y >> 2) == px0 + 1;
        bool r2 = (c2 & 2) && (v.z >> 2) == px0 + 2;
        bool r3 = (c3 & 2) && (v.w >> 2) == px0 + 3;
        if (r0) { if (c0 == 2) n2++; else n3++; }
        if (r1) { if (c1 == 2) n2++; else n3++; }
        if (r2) { if (c2 == 2) n2++; else n3++; }
        if (r3) { if (c3 == 2) n2++; else n3++; }
        if (r == 0 || r == TROWS - 1) {    // tile-boundary rows: dense, root-compressed
            int4 ov;
            ov.x = (c0 & 2) ? (((lbase + find_root_p(lab, px0    )) << 2) | c0) : (((lbase + px0    ) << 2) | c0);
            ov.y = (c1 & 2) ? (((lbase + find_root_p(lab, px0 + 1)) << 2) | c1) : (((lbase + px0 + 1) << 2) | c1);
            ov.z = (c2 & 2) ? (((lbase + find_root_p(lab, px0 + 2)) << 2) | c2) : (((lbase + px0 + 2) << 2) | c2);
            ov.w = (c3 & 2) ? (((lbase + find_root_p(lab, px0 + 3)) << 2) | c3) : (((lbase + px0 + 3) << 2) | c3);
            *(int4*)&gl[px0] = ov;
        } else {                           // interior: only root self-pointers
            if (r0) gl[px0]     = ((lbase + px0)     << 2) | c0;
            if (r1) gl[px0 + 1] = ((lbase + px0 + 1) << 2) | c1;
            if (r2) gl[px0 + 2] = ((lbase + px0 + 2) << 2) | c2;
            if (r3) gl[px0 + 3] = ((lbase + px0 + 3) << 2) | c3;
        }
    }
    // reduce root counts -> one padded atomic per (block, class)
    for (int off = 32; off; off >>= 1) {
        n2 += __shfl_down(n2, off, 64);
        n3 += __shfl_down(n3, off, 64);
    }
    if (lane == 0) { s2[wid] = n2; s3[wid] = n3; }
    __syncthreads();
    if (tid == 0) {
        int t2 = s2[0] + s2[1] + s2[2];
        int t3 = s3[0] + s3[1] + s3[2];
        if (t2) atomicAdd(&counts[(m * 2 + 0) * CSLOT], t2);
        if (t3) atomicAdd(&counts[(m * 2 + 1) * CSLOT], t3);
    }
}

// Cross-tile boundary edges on packed labels, 2 columns per thread (int2).
// Run-dedup: skip a union when the packed-value pair equals the previous
// column's pair (same run pair -> redundant; dedup is an optimization only,
// duplicate unions are idempotent and count only real merges).
// blockIdx.y = map -> counts index is block-uniform.
__global__ __launch_bounds__(256) void boundary_k(int* __restrict__ labels,
                                                  int* __restrict__ counts, int m0) {
    __shared__ int s2[4], s3[4];
    const int HM = NB * (W / 2);               // 48768 col-pairs per map
    int i    = blockIdx.x * 256 + threadIdx.x;
    int mc   = blockIdx.y;
    int m    = m0 + mc;
    int lane = threadIdx.x & 63;

    int m2 = 0, m3 = 0;
    if (i < HM) {
        int b   = i / (W / 2);
        int col = (i - b * (W / 2)) * 2;
        int* L  = labels + (size_t)mc * PIX;
        int p1  = b * TPX + (TROWS - 1) * W + col;   // tile b, last row
        int p2  = p1 + W;                            // tile b+1, row 0
        int2 va = *(const int2*)&L[p1];
        int2 vb = *(const int2*)&L[p2];
        int pay = __shfl_up(va.y, 1), pby = __shfl_up(vb.y, 1);
        int c0 = va.x & 3;
        if (c0 == (vb.x & 3) && (c0 & 2)) {
            bool red = (lane > 0) && (pay == va.x) && (pby == vb.x);
            if (!red && unite_gp(L, p1, p2, c0)) { if (c0 == 2) m2++; else m3++; }
        }
        int c1 = va.y & 3;
        if (c1 == (vb.y & 3) && (c1 & 2)) {
            bool red = (va.x == va.y) && (vb.x == vb.y);
            if (!red && unite_gp(L, p1 + 1, p2 + 1, c1)) { if (c1 == 2) m2++; else m3++; }
        }
    }
    for (int off = 32; off; off >>= 1) {
        m2 += __shfl_down(m2, off, 64);
        m3 += __shfl_down(m3, off, 64);
    }
    int wid = threadIdx.x >> 6;
    if (lane == 0) { s2[wid] = m2; s3[wid] = m3; }
    __syncthreads();
    if (threadIdx.x == 0) {
        int t2 = s2[0] + s2[1] + s2[2] + s2[3];
        int t3 = s3[0] + s3[1] + s3[2] + s3[3];
        if (t2) atomicSub(&counts[(m * 2 + 0) * CSLOT], t2);
        if (t3) atomicSub(&counts[(m * 2 + 1) * CSLOT], t3);
    }
}

__global__ void final_k(const int* __restrict__ counts, float* __restrict__ out) {
    float s = 0.0f;
    for (int b = 0; b < 8; ++b) {
        float a2 = (float)counts[(b * 2 + 0) * CSLOT];
        float a3 = (float)counts[(b * 2 + 1) * CSLOT];
        float p2 = (float)counts[((8 + b) * 2 + 0) * CSLOT];
        float p3 = (float)counts[((8 + b) * 2 + 1) * CSLOT];
        float t2 = 1.0f - 2.0f * fminf(p2, a2) / (a2 + p2);
        float t3 = 1.0f - 2.0f * fminf(p3, a3) / (a3 + p3);
        s += t2 + t3;
    }
    out[0] = 0.5f * s;
}

// ---------------- launch ----------------

extern "C" void kernel_launch(void* const* d_in, const int* in_sizes, int n_in,
                              void* d_out, int out_size, void* d_ws, size_t ws_size,
                              hipStream_t stream) {
    const float* pred = (const float*)d_in[0];   // (8,4,1,768,768) f32
    const int*   anno = (const int*)d_in[1];     // (8,1,768,768) i32
    float* out = (float*)d_out;

    int* counts = (int*)d_ws;                    // 32*CSLOT ints = 2 KB
    char* base  = (char*)d_ws + 4096;

    const size_t per_map = (size_t)PIX * 4;      // packed labels only
    size_t avail = (ws_size > 4096) ? ws_size - 4096 : 0;
    int K = (int)(avail / per_map);
    if (K > NMAPS) K = NMAPS;
    if (K < 1)     K = 1;    // best effort; needs ~2.4 MB min

    hipMemsetAsync(counts, 0, 32 * CSLOT * sizeof(int), stream);

    const int HM = NB * (W / 2);                 // 48768 col-pairs per map
    for (int m0 = 0; m0 < NMAPS; m0 += K) {
        int nm = NMAPS - m0; if (nm > K) nm = K;
        int* labels = (int*)base;
        fused_k   <<<dim3(nm * NT), 192, 0, stream>>>(pred, anno, labels, counts, m0);
        boundary_k<<<dim3((HM + 255) / 256, nm), 256, 0, stream>>>(labels, counts, m0);
    }
    final_k<<<1, 1, 0, stream>>>(counts, out);
}

// Round 11
// 57.502 us; speedup vs baseline: 1.1542x; 1.1542x over previous
//
#include <hip/hip_runtime.h>

#define W     768
#define PIX   (768*768)
#define NMAPS 16            // 0..7 anno, 8..15 pred-argmax
#define TROWS 6
#define TPX   (TROWS*W)     // 4608 px per tile
#define NT    (768/TROWS)   // 128 tiles per map
#define NB    (NT-1)        // 127 tile boundaries per map
#define NSEG  (TPX/64)      // 72 wave-segments per tile (12 per row)
#define NIT   (NSEG/4)      // 18 iterations per wave
#define CSLOT 16            // ints per counter slot (64 B line)

// Labels are PACKED everywhere: (label<<2) | cls. Within a component all
// pixels share cls, and min over packed == min over label -> cls bits are
// invariant under atomicMin unions.

__device__ __forceinline__ int find_root_p(volatile int* L, int x) {
    int y = L[x] >> 2;
    while (y != x) { x = y; y = L[x] >> 2; }
    return x;
}

__device__ __forceinline__ void unite_p(int* L, int a, int b, int c) {
    volatile int* Lv = L;
    while (true) {
        a = find_root_p(Lv, a);
        b = find_root_p(Lv, b);
        if (a == b) return;
        if (a > b) { int t = a; a = b; b = t; }
        int old = atomicMin(&L[b], (a << 2) | c);
        if ((old >> 2) == b) return;
        b = old >> 2;
    }
}

// Packed global unite; true iff a link event occurred (two roots merged).
// Parents only decrease -> acyclic; each index loses rootness at most once,
// so #link events == #merges exactly, independent of atomic ordering.
__device__ __forceinline__ bool unite_gp(int* L, int a, int b, int c) {
    volatile int* Lv = L;
    while (true) {
        a = find_root_p(Lv, a);
        b = find_root_p(Lv, b);
        if (a == b) return false;
        if (a > b) { int t = a; a = b; b = t; }
        int old = atomicMin(&L[b], (a << 2) | c);
        if ((old >> 2) == b) return true;
        b = old >> 2;
    }
}

// ---------------- kernels ----------------

// One block per (map, 6-row tile), 256 threads = 4 waves (R9 structure).
// Wave wid owns column-segments == wid (mod 4) of EVERY row -> vertical
// neighbors are same-wave; per-run-pair vertical unions fire inside phase A
// from register-carried prev-row state. EXPLICIT DEPTH-1 PREFETCH: iteration
// it issues it+1's global loads before it's dependent compute — the compiler
// cannot hoist loads across unite_p's atomic loop on its own (VGPR=16 in R9
// showed zero load pipelining). Phase 3 writes SPARSE global labels:
// tile-boundary rows (root-compressed) + root self-pointers elsewhere.
__global__ __launch_bounds__(256) void fused_k(const float* __restrict__ pred,
                                               const int*   __restrict__ anno,
                                               int* __restrict__ labels,
                                               int* __restrict__ counts, int m0) {
    __shared__ int lab[TPX];               // 18 KB packed (label<<2)|cls
    __shared__ int s2[4], s3[4];

    int mc   = blockIdx.x / NT;
    int t    = blockIdx.x - mc * NT;
    int m    = m0 + mc;
    int tid  = threadIdx.x;
    int wid  = tid >> 6;
    int lane = tid & 63;

    int pc[3] = {0, 0, 0};                 // prev-row class per strip slot
    int pm[3] = {0, 0, 0};                 // prev-row run-start lane per slot

    const int*   asrc = anno + (size_t)m * PIX + (size_t)t * TPX;
    const float* psrc = pred + (size_t)(m < 8 ? 0 : (m - 8)) * 4 * PIX + (size_t)t * TPX;
    bool is_anno = (m < 8);

    // ---- prefetch it=0 ----
    int   na = 0;
    float nv0 = 0.f, nv1 = 0.f, nv2 = 0.f, nv3 = 0.f;
    {
        int px = wid * 64 + lane;
        if (is_anno) {
            na = asrc[px];
        } else {
            nv0 = psrc[px];
            nv1 = psrc[(size_t)PIX + px];
            nv2 = psrc[(size_t)2 * PIX + px];
            nv3 = psrc[(size_t)3 * PIX + px];
        }
    }

    // ---- phase A: decode cls, run-start init, in-register vertical unions ----
    #pragma unroll
    for (int it = 0; it < NIT; ++it) {
        int seg = wid + 4 * it;
        int px  = seg * 64 + lane;
        // consume prefetched values
        int   ca = na;
        float v0 = nv0, v1 = nv1, v2 = nv2, v3 = nv3;
        // issue next iteration's loads BEFORE dependent compute
        if (it + 1 < NIT) {
            int pxn = px + 256;            // (seg+4)*64 + lane
            if (is_anno) {
                na = asrc[pxn];
            } else {
                nv0 = psrc[pxn];
                nv1 = psrc[(size_t)PIX + pxn];
                nv2 = psrc[(size_t)2 * PIX + pxn];
                nv3 = psrc[(size_t)3 * PIX + pxn];
            }
        }
        int c;
        if (is_anno) {
            c = ca & 3;
        } else {
            c = 0; float bv = v0;           // strict '>' = first-max (jnp.argmax)
            if (v1 > bv) { bv = v1; c = 1; }
            if (v2 > bv) { bv = v2; c = 2; }
            if (v3 > bv) { bv = v3; c = 3; }
        }
        int cl = __shfl_up(c, 1);
        unsigned long long bm = __ballot(lane == 0 || c != cl);
        int ms = 63 - __clzll(bm & ((2ULL << lane) - 1));   // run-start lane
        lab[px] = ((seg * 64 + ms) << 2) | c;
        const int sl = it % 3;              // static under full unroll
        if (it >= 3) {                      // row >= 1: wave-private strip union
            if ((c & 2) && c == pc[sl]) {
                int mx = ms > pm[sl] ? ms : pm[sl];
                if (lane == mx) unite_p(lab, px - W, px, c);
            }
        }
        pc[sl] = c; pm[sl] = ms;
    }
    __syncthreads();

    // ---- stitch phase: 66 cross-strip horizontal joins ----
    if (tid < TROWS * 11) {
        int row = tid / 11, j = tid % 11;
        int px  = row * W + (j + 1) * 64;
        int v = lab[px], c = v & 3;
        if (c & 2) {
            int vl = lab[px - 1];
            if ((vl & 3) == c) unite_p(lab, px - 1, px, c);
        }
    }
    __syncthreads();

    // ---- phase 3: count roots (1 read, no find), sparse label writes ----
    int c2 = 0, c3 = 0;
    int lbase = t * TPX;                    // map-local base of this tile
    int* gl = labels + (size_t)mc * PIX + lbase;
    #pragma unroll
    for (int it = 0; it < NIT; ++it) {
        int seg = wid + 4 * it;
        int px  = seg * 64 + lane;
        int v   = lab[px];
        int c   = v & 3;
        bool incls  = (c & 2) != 0;
        bool isroot = incls && ((v >> 2) == px);
        if (isroot) { if (c == 2) c2++; else c3++; }
        if (it < 3 || it >= NIT - 3) {      // tile rows 0 and TROWS-1
            int outv;
            if (incls) {
                int r = find_root_p(lab, px);
                outv = ((lbase + r) << 2) | c;
            } else {
                outv = ((lbase + px) << 2) | c;
            }
            gl[px] = outv;
        } else if (isroot) {
            gl[px] = ((lbase + px) << 2) | c;   // self-pointer for chain interiors
        }
    }
    // reduce root counts -> one padded atomic per (block, class)
    for (int off = 32; off; off >>= 1) {
        c2 += __shfl_down(c2, off, 64);
        c3 += __shfl_down(c3, off, 64);
    }
    if (lane == 0) { s2[wid] = c2; s3[wid] = c3; }
    __syncthreads();
    if (tid == 0) {
        int t2 = s2[0] + s2[1] + s2[2] + s2[3];
        int t3 = s3[0] + s3[1] + s3[2] + s3[3];
        if (t2) atomicAdd(&counts[(m * 2 + 0) * CSLOT], t2);
        if (t3) atomicAdd(&counts[(m * 2 + 1) * CSLOT], t3);
    }
}

// Cross-tile boundary edges on packed labels, 2 columns per thread (int2).
// Run-dedup: skip a union when the packed-value pair equals the previous
// column's pair (same run pair -> redundant; dedup is an optimization only,
// duplicate unions are idempotent and count only real merges).
// blockIdx.y = map -> counts index is block-uniform.
__global__ __launch_bounds__(256) void boundary_k(int* __restrict__ labels,
                                                  int* __restrict__ counts, int m0) {
    __shared__ int s2[4], s3[4];
    const int HM = NB * (W / 2);               // 48768 col-pairs per map
    int i    = blockIdx.x * 256 + threadIdx.x;
    int mc   = blockIdx.y;
    int m    = m0 + mc;
    int lane = threadIdx.x & 63;

    int m2 = 0, m3 = 0;
    if (i < HM) {
        int b   = i / (W / 2);
        int col = (i - b * (W / 2)) * 2;
        int* L  = labels + (size_t)mc * PIX;
        int p1  = b * TPX + (TROWS - 1) * W + col;   // tile b, last row
        int p2  = p1 + W;                            // tile b+1, row 0
        int2 va = *(const int2*)&L[p1];
        int2 vb = *(const int2*)&L[p2];
        int pay = __shfl_up(va.y, 1), pby = __shfl_up(vb.y, 1);
        int c0 = va.x & 3;
        if (c0 == (vb.x & 3) && (c0 & 2)) {
            bool red = (lane > 0) && (pay == va.x) && (pby == vb.x);
            if (!red && unite_gp(L, p1, p2, c0)) { if (c0 == 2) m2++; else m3++; }
        }
        int c1 = va.y & 3;
        if (c1 == (vb.y & 3) && (c1 & 2)) {
            bool red = (va.x == va.y) && (vb.x == vb.y);
            if (!red && unite_gp(L, p1 + 1, p2 + 1, c1)) { if (c1 == 2) m2++; else m3++; }
        }
    }
    for (int off = 32; off; off >>= 1) {
        m2 += __shfl_down(m2, off, 64);
        m3 += __shfl_down(m3, off, 64);
    }
    int wid = threadIdx.x >> 6;
    if (lane == 0) { s2[wid] = m2; s3[wid] = m3; }
    __syncthreads();
    if (threadIdx.x == 0) {
        int t2 = s2[0] + s2[1] + s2[2] + s2[3];
        int t3 = s3[0] + s3[1] + s3[2] + s3[3];
        if (t2) atomicSub(&counts[(m * 2 + 0) * CSLOT], t2);
        if (t3) atomicSub(&counts[(m * 2 + 1) * CSLOT], t3);
    }
}

__global__ void final_k(const int* __restrict__ counts, float* __restrict__ out) {
    float s = 0.0f;
    for (int b = 0; b < 8; ++b) {
        float a2 = (float)counts[(b * 2 + 0) * CSLOT];
        float a3 = (float)counts[(b * 2 + 1) * CSLOT];
        float p2 = (float)counts[((8 + b) * 2 + 0) * CSLOT];
        float p3 = (float)counts[((8 + b) * 2 + 1) * CSLOT];
        float t2 = 1.0f - 2.0f * fminf(p2, a2) / (a2 + p2);
        float t3 = 1.0f - 2.0f * fminf(p3, a3) / (a3 + p3);
        s += t2 + t3;
    }
    out[0] = 0.5f * s;
}

// ---------------- launch ----------------

extern "C" void kernel_launch(void* const* d_in, const int* in_sizes, int n_in,
                              void* d_out, int out_size, void* d_ws, size_t ws_size,
                              hipStream_t stream) {
    const float* pred = (const float*)d_in[0];   // (8,4,1,768,768) f32
    const int*   anno = (const int*)d_in[1];     // (8,1,768,768) i32
    float* out = (float*)d_out;

    int* counts = (int*)d_ws;                    // 32*CSLOT ints = 2 KB
    char* base  = (char*)d_ws + 4096;

    const size_t per_map = (size_t)PIX * 4;      // packed labels only
    size_t avail = (ws_size > 4096) ? ws_size - 4096 : 0;
    int K = (int)(avail / per_map);
    if (K > NMAPS) K = NMAPS;
    if (K < 1)     K = 1;    // best effort; needs ~2.4 MB min

    hipMemsetAsync(counts, 0, 32 * CSLOT * sizeof(int), stream);

    const int HM = NB * (W / 2);                 // 48768 col-pairs per map
    for (int m0 = 0; m0 < NMAPS; m0 += K) {
        int nm = NMAPS - m0; if (nm > K) nm = K;
        int* labels = (int*)base;
        fused_k   <<<dim3(nm * NT), 256, 0, stream>>>(pred, anno, labels, counts, m0);
        boundary_k<<<dim3((HM + 255) / 256, nm), 256, 0, stream>>>(labels, counts, m0);
    }
    final_k<<<1, 1, 0, stream>>>(counts, out);
}